// Round 6
// baseline (373.109 us; speedup 1.0000x reference)
//
#include <hip/hip_runtime.h>
#include <hip/hip_bf16.h>

// fp32 problem: b=2, s=2048, D=2048, 32 q-heads / 8 kv-groups, d=64
#define TOKENS   4096
#define SEQ      2048
#define DMODEL   2048
#define CONCAT   3072
#define NHEADS   32
#define NGROUPS  8
#define HPERG    4
#define CQ       2048
#define CK       512

typedef __attribute__((ext_vector_type(8))) short bf16x8;
typedef __attribute__((ext_vector_type(4))) float f32x4;

__device__ __forceinline__ ushort f2bf(float f) {
    __hip_bfloat16 h = __float2bfloat16(f);
    return __builtin_bit_cast(ushort, h);
}

#define GLOBAL_TO_LDS16(g, l)                                                  \
    __builtin_amdgcn_global_load_lds(                                          \
        (const __attribute__((address_space(1))) void*)(g),                    \
        (__attribute__((address_space(3))) void*)(l), 16, 0, 0)

// ---------------- RMSNorm: one block (256 thr) per token, bf16 out -------
__global__ void rmsnorm_kernel(const float* __restrict__ x,
                               const float* __restrict__ w,
                               ushort* __restrict__ y_bf) {
    int t = blockIdx.x;
    const float4* xr = (const float4*)(x + (size_t)t * DMODEL);
    float4 v[2];
    float ss = 0.f;
#pragma unroll
    for (int i = 0; i < 2; i++) {
        v[i] = xr[threadIdx.x + i * 256];
        ss += v[i].x * v[i].x + v[i].y * v[i].y + v[i].z * v[i].z + v[i].w * v[i].w;
    }
#pragma unroll
    for (int off = 32; off >= 1; off >>= 1) ss += __shfl_xor(ss, off);
    __shared__ float red[4];
    int wid = threadIdx.x >> 6;
    if ((threadIdx.x & 63) == 0) red[wid] = ss;
    __syncthreads();
    float total = red[0] + red[1] + red[2] + red[3];
    float scale = rsqrtf(total * (1.0f / DMODEL) + 1e-6f);
    const float4* wr = (const float4*)w;
    ushort4* yr = (ushort4*)(y_bf + (size_t)t * DMODEL);
#pragma unroll
    for (int i = 0; i < 2; i++) {
        int c = threadIdx.x + i * 256;
        float4 wv = wr[c];
        ushort4 o;
        o.x = f2bf(v[i].x * scale * wv.x);
        o.y = f2bf(v[i].y * scale * wv.y);
        o.z = f2bf(v[i].z * scale * wv.z);
        o.w = f2bf(v[i].w * scale * wv.w);
        yr[c] = o;
    }
}

// ---------------- fp32 -> bf16 cast (weights) ----------------------------
__global__ void pack_bf16_kernel(const float* __restrict__ src,
                                 ushort* __restrict__ dst, int n4) {
    int i = blockIdx.x * 256 + threadIdx.x;
    if (i < n4) {
        float4 v = ((const float4*)src)[i];
        ushort4 o;
        o.x = f2bf(v.x); o.y = f2bf(v.y); o.z = f2bf(v.z); o.w = f2bf(v.w);
        ((ushort4*)dst)[i] = o;
    }
}

// ---------------- GEMM-in + fused RoPE/pack epilogue ---------------------
// y_bf[4096,2048] * w_in_bf[3072,2048]^T; each wave's 64-col strip is one
// head/group, so RoPE pairs (d, d+32) sit in acc[mi][jt] / acc[mi][jt+2]
// of the same lane. Writes Qb[head][s][d] (pre-scaled), Kb[grp][s][d],
// Vb[grp][d][s] (transpose free via r-packing) directly.
__global__ __launch_bounds__(256) void gemm_qkv_mfma(
        const ushort* __restrict__ A, const ushort* __restrict__ B,
        ushort* __restrict__ Qb, ushort* __restrict__ Kb,
        ushort* __restrict__ Vb) {
    __shared__ __align__(16) ushort As[128 * 64];
    __shared__ __align__(16) ushort Bs[128 * 64];

    const int bm = blockIdx.y * 128, bn = blockIdx.x * 128;
    const int w = threadIdx.x >> 6, lane = threadIdx.x & 63;
    const int n = lane & 15, quad = lane >> 4;
    const int wr = (w & 1) * 64, wc = (w >> 1) * 64;
    const int r8 = lane >> 3;
    const int kb = (lane & 7) ^ r8;

    f32x4 acc[4][4] = {};

    for (int k0 = 0; k0 < DMODEL; k0 += 64) {
        __syncthreads();
#pragma unroll
        for (int i = 0; i < 4; i++) {
            int rbase = (w * 4 + i) * 8;
            const ushort* ga = A + (size_t)(bm + rbase + r8) * DMODEL + k0 + kb * 8;
            GLOBAL_TO_LDS16(ga, As + rbase * 64);
            const ushort* gb = B + (size_t)(bn + rbase + r8) * DMODEL + k0 + kb * 8;
            GLOBAL_TO_LDS16(gb, Bs + rbase * 64);
        }
        __syncthreads();
#pragma unroll
        for (int ks = 0; ks < 2; ks++) {
            bf16x8 af[4], bfr[4];
            int kblk = ks * 4 + quad;
#pragma unroll
            for (int mi = 0; mi < 4; mi++) {
                int row = wr + mi * 16 + n;
                af[mi] = *(const bf16x8*)(As + (row * 8 + (kblk ^ (row & 7))) * 8);
            }
#pragma unroll
            for (int ni = 0; ni < 4; ni++) {
                int row = wc + ni * 16 + n;
                bfr[ni] = *(const bf16x8*)(Bs + (row * 8 + (kblk ^ (row & 7))) * 8);
            }
#pragma unroll
            for (int mi = 0; mi < 4; mi++)
#pragma unroll
                for (int ni = 0; ni < 4; ni++)
                    acc[mi][ni] = __builtin_amdgcn_mfma_f32_16x16x32_bf16(
                        af[mi], bfr[ni], acc[mi][ni], 0, 0, 0);
        }
    }

    const int cb = bn + wc;           // wave's first output column
    const int row0 = bm + wr;         // wave's first output row (token)
    const int b = row0 >> 11;
    const float LOG2_THETA = 13.287712379549449f;
    const float QSCALE = 0.18033688011112042f;   // 0.125 * log2(e)

    if (cb < CQ + CK) {               // Q or K: RoPE path
        bool isQ = (cb < CQ);
        ushort* base;
        if (isQ) {
            int head = cb >> 6;
            base = Qb + (size_t)((b * 8 + (head >> 2)) * 4 + (head & 3)) * (SEQ * 64);
        } else {
            int grp = (cb - CQ) >> 6;
            base = Kb + (size_t)(b * 8 + grp) * (SEQ * 64);
        }
        float inv0 = exp2f(-((float)n / 32.f) * LOG2_THETA);
        float inv1 = exp2f(-((float)(16 + n) / 32.f) * LOG2_THETA);
        float osc = isQ ? QSCALE : 1.0f;
#pragma unroll
        for (int mi = 0; mi < 4; mi++)
#pragma unroll
            for (int r = 0; r < 4; r++) {
                int s = (row0 + mi * 16 + quad * 4 + r) & (SEQ - 1);
#pragma unroll
                for (int jt = 0; jt < 2; jt++) {
                    float ang = (float)s * (jt ? inv1 : inv0);
                    float sn, c;
                    __sincosf(ang, &sn, &c);
                    float a = acc[mi][jt][r], bb = acc[mi][jt + 2][r];
                    base[(size_t)s * 64 + jt * 16 + n]      = f2bf((a * c - bb * sn) * osc);
                    base[(size_t)s * 64 + jt * 16 + n + 32] = f2bf((bb * c + a * sn) * osc);
                }
            }
    } else {                          // V: transpose via r-packing
        int grp = (cb - CQ - CK) >> 6;
        ushort* base = Vb + (size_t)(b * 8 + grp) * (64 * SEQ);
#pragma unroll
        for (int mi = 0; mi < 4; mi++) {
            int s0 = (row0 + mi * 16 + quad * 4) & (SEQ - 1);
#pragma unroll
            for (int ni = 0; ni < 4; ni++) {
                int d = ni * 16 + n;
                ushort4 pk;
                pk.x = f2bf(acc[mi][ni][0]);
                pk.y = f2bf(acc[mi][ni][1]);
                pk.z = f2bf(acc[mi][ni][2]);
                pk.w = f2bf(acc[mi][ni][3]);
                *(ushort4*)(base + (size_t)d * SEQ + s0) = pk;
            }
        }
    }
}

// ---------------- MFMA GEMM-out: OUT = X + A*B^T (bf16 in, fp32 out) -----
__global__ __launch_bounds__(256) void gemm_out_mfma(
        const ushort* __restrict__ A, const ushort* __restrict__ B,
        const float* __restrict__ X, float* __restrict__ OUT,
        int M, int N, int K) {
    __shared__ __align__(16) ushort As[128 * 64];
    __shared__ __align__(16) ushort Bs[128 * 64];

    const int bm = blockIdx.y * 128, bn = blockIdx.x * 128;
    const int w = threadIdx.x >> 6, lane = threadIdx.x & 63;
    const int n = lane & 15, quad = lane >> 4;
    const int wr = (w & 1) * 64, wc = (w >> 1) * 64;
    const int r8 = lane >> 3;
    const int kb = (lane & 7) ^ r8;

    f32x4 acc[4][4] = {};

    for (int k0 = 0; k0 < K; k0 += 64) {
        __syncthreads();
#pragma unroll
        for (int i = 0; i < 4; i++) {
            int rbase = (w * 4 + i) * 8;
            const ushort* ga = A + (size_t)(bm + rbase + r8) * K + k0 + kb * 8;
            GLOBAL_TO_LDS16(ga, As + rbase * 64);
            const ushort* gb = B + (size_t)(bn + rbase + r8) * K + k0 + kb * 8;
            GLOBAL_TO_LDS16(gb, Bs + rbase * 64);
        }
        __syncthreads();
#pragma unroll
        for (int ks = 0; ks < 2; ks++) {
            bf16x8 af[4], bfr[4];
            int kblk = ks * 4 + quad;
#pragma unroll
            for (int mi = 0; mi < 4; mi++) {
                int row = wr + mi * 16 + n;
                af[mi] = *(const bf16x8*)(As + (row * 8 + (kblk ^ (row & 7))) * 8);
            }
#pragma unroll
            for (int ni = 0; ni < 4; ni++) {
                int row = wc + ni * 16 + n;
                bfr[ni] = *(const bf16x8*)(Bs + (row * 8 + (kblk ^ (row & 7))) * 8);
            }
#pragma unroll
            for (int mi = 0; mi < 4; mi++)
#pragma unroll
                for (int ni = 0; ni < 4; ni++)
                    acc[mi][ni] = __builtin_amdgcn_mfma_f32_16x16x32_bf16(
                        af[mi], bfr[ni], acc[mi][ni], 0, 0, 0);
        }
    }

#pragma unroll
    for (int mi = 0; mi < 4; mi++)
#pragma unroll
        for (int ni = 0; ni < 4; ni++)
#pragma unroll
            for (int r = 0; r < 4; r++) {
                int row = bm + wr + mi * 16 + quad * 4 + r;
                int col = bn + wc + ni * 16 + n;
                size_t idx = (size_t)row * N + col;
                OUT[idx] = X[idx] + acc[mi][ni][r];
            }
}

// ---------------- MFMA flash attention, v3: barrier-free -----------------
// One wave per 32-query strip. K-frags (A-op of S^T) and V-frags (B-op of
// PV, [d][s] layout) are 16B-contiguous in global -> load direct (L2-hot,
// 8MB working set). Only P round-trips through per-wave LDS. No barriers.
__global__ __launch_bounds__(256) void attn_mfma_kernel(
        const ushort* __restrict__ Qb, const ushort* __restrict__ Kb,
        const ushort* __restrict__ Vb, ushort* __restrict__ o_bf) {
    __shared__ __align__(16) uint Pl[4][1056];

    int blk = blockIdx.x;
    int sblk = 15 - (blk >> 6);         // longest strips dispatch first
    int bgh = blk & 63;
    int h = bgh & 3, g = (bgh >> 2) & 7, b = bgh >> 5;
    int w = threadIdx.x >> 6, lane = threadIdx.x & 63;
    int n = lane & 15, quad = lane >> 4;
    int strip = w * 16 + sblk;          // interleaved: balances block runtimes
    int qw = strip * 32;

    const ushort* Qh = Qb + (size_t)((b * 8 + g) * 4 + h) * (SEQ * 64);
    const ushort* Kg = Kb + (size_t)(b * 8 + g) * (SEQ * 64);
    const ushort* Vg = Vb + (size_t)(b * 8 + g) * (64 * SEQ);

    bf16x8 aq[2][2];
#pragma unroll
    for (int qg = 0; qg < 2; qg++)
#pragma unroll
        for (int ks = 0; ks < 2; ks++)
            aq[qg][ks] = *(const bf16x8*)(
                Qh + (size_t)(qw + qg * 16 + n) * 64 + ks * 32 + quad * 8);

    f32x4 od[2][4] = {};
    f32x4 od4[2] = {};

    short onev = (n == 0) ? (short)0x3F80 : (short)0;
    bf16x8 bones = {onev, onev, onev, onev, onev, onev, onev, onev};

    uint* Pw = Pl[w];
    int nkt = (strip >> 1) + 1;
    for (int kt = 0; kt < nkt; kt++) {
        // S^T = K Q^T (operand swap): frags straight from global
#pragma unroll
        for (int t16k = 0; t16k < 4; t16k++) {
            const ushort* kp = Kg + (size_t)(kt * 64 + t16k * 16 + n) * 64 + quad * 8;
            bf16x8 kf0 = *(const bf16x8*)kp;
            bf16x8 kf1 = *(const bf16x8*)(kp + 32);
            int key0 = kt * 64 + t16k * 16 + quad * 4;
#pragma unroll
            for (int qg = 0; qg < 2; qg++) {
                f32x4 c = {};
                c = __builtin_amdgcn_mfma_f32_16x16x32_bf16(kf0, aq[qg][0], c, 0, 0, 0);
                c = __builtin_amdgcn_mfma_f32_16x16x32_bf16(kf1, aq[qg][1], c, 0, 0, 0);
                int qrow = qw + qg * 16 + n;
                float p[4];
                if (kt * 64 + 63 > qw + qg * 16) {      // tile may mask
#pragma unroll
                    for (int r = 0; r < 4; r++)
                        p[r] = (key0 + r <= qrow) ? __builtin_amdgcn_exp2f(c[r]) : 0.f;
                } else {
#pragma unroll
                    for (int r = 0; r < 4; r++)
                        p[r] = __builtin_amdgcn_exp2f(c[r]);
                }
                uint d0 = ((uint)f2bf(p[1]) << 16) | f2bf(p[0]);
                uint d1 = ((uint)f2bf(p[3]) << 16) | f2bf(p[2]);
                int base = ((t16k * 2 + (quad >> 1)) * 33 + qg * 16 + n) * 4
                           + (quad & 1) * 2;
                Pw[base]     = d0;
                Pw[base + 1] = d1;
            }
        }

        // O += P V (+ ones column accumulates l); V frags straight from global
#pragma unroll
        for (int kb2 = 0; kb2 < 2; kb2++) {
            bf16x8 bv[4];
#pragma unroll
            for (int dt = 0; dt < 4; dt++)
                bv[dt] = *(const bf16x8*)(
                    Vg + (size_t)(dt * 16 + n) * SEQ + kt * 64 + (kb2 * 4 + quad) * 8);
#pragma unroll
            for (int qg = 0; qg < 2; qg++) {
                bf16x8 ap = *(const bf16x8*)(
                    (const ushort*)Pw + ((kb2 * 4 + quad) * 33 + qg * 16 + n) * 8);
#pragma unroll
                for (int dt = 0; dt < 4; dt++)
                    od[qg][dt] = __builtin_amdgcn_mfma_f32_16x16x32_bf16(
                        ap, bv[dt], od[qg][dt], 0, 0, 0);
                od4[qg] = __builtin_amdgcn_mfma_f32_16x16x32_bf16(
                    ap, bones, od4[qg], 0, 0, 0);
            }
        }
    }

#pragma unroll
    for (int qg = 0; qg < 2; qg++) {
        float linv[4];
#pragma unroll
        for (int r = 0; r < 4; r++) {
            float lv = __shfl(od4[qg][r], lane & 48);
            linv[r] = __builtin_amdgcn_rcpf(lv);
        }
#pragma unroll
        for (int dt = 0; dt < 4; dt++)
#pragma unroll
            for (int r = 0; r < 4; r++) {
                int q = qw + qg * 16 + quad * 4 + r;
                int col = (g * 4 + h) * 64 + dt * 16 + n;
                o_bf[(size_t)(b * SEQ + q) * DMODEL + col] =
                    f2bf(od[qg][dt][r] * linv[r]);
            }
    }
}

extern "C" void kernel_launch(void* const* d_in, const int* in_sizes, int n_in,
                              void* d_out, int out_size, void* d_ws, size_t ws_size,
                              hipStream_t stream) {
    const float* x     = (const float*)d_in[0];
    const float* w_in  = (const float*)d_in[1];
    const float* w_out = (const float*)d_in[2];
    const float* rms_w = (const float*)d_in[3];
    float* out = (float*)d_out;

    // Workspace (flat, 76 MB — no fp32 qkv buffer anymore):
    const size_t MB = 1024 * 1024;
    char* ws = (char*)d_ws;
    ushort* y_bf     = (ushort*)ws;              // 16 MB
    ushort* w_in_bf  = (ushort*)(ws + 16 * MB);  // 12 MB
    ushort* Qb       = (ushort*)(ws + 28 * MB);  // 16 MB
    ushort* Kb       = (ushort*)(ws + 44 * MB);  //  4 MB
    ushort* Vb       = (ushort*)(ws + 48 * MB);  //  4 MB
    ushort* o_bf     = (ushort*)(ws + 52 * MB);  // 16 MB
    ushort* w_out_bf = (ushort*)(ws + 68 * MB);  //  8 MB

    rmsnorm_kernel<<<TOKENS, 256, 0, stream>>>(x, rms_w, y_bf);
    pack_bf16_kernel<<<(CONCAT * DMODEL / 4 + 255) / 256, 256, 0, stream>>>(
        w_in, w_in_bf, CONCAT * DMODEL / 4);

    gemm_qkv_mfma<<<dim3(CONCAT / 128, TOKENS / 128), 256, 0, stream>>>(
        y_bf, w_in_bf, Qb, Kb, Vb);

    pack_bf16_kernel<<<(DMODEL * DMODEL / 4 + 255) / 256, 256, 0, stream>>>(
        w_out, w_out_bf, DMODEL * DMODEL / 4);

    attn_mfma_kernel<<<1024, 256, 0, stream>>>(Qb, Kb, Vb, o_bf);

    gemm_out_mfma<<<dim3(DMODEL / 128, TOKENS / 128), 256, 0, stream>>>(
        o_bf, w_out_bf, x, out, TOKENS, DMODEL, DMODEL);
}